// Round 1
// baseline (560.488 us; speedup 1.0000x reference)
//
#include <hip/hip_runtime.h>
#include <math.h>

// Problem constants (also derived from in_sizes at launch)
#define HEADS 8
#define DHEAD 128
#define CMODEL 1024   // HEADS*DHEAD

__device__ __forceinline__ float gelu_exact(float x) {
    return 0.5f * x * (1.0f + erff(x * 0.70710678118654752440f));
}

// ---------------- h = x @ gat_w  (x: [N,4], w: [4,1024]) ----------------
__global__ void __launch_bounds__(256) k_h(const float* __restrict__ x,
                                           const float* __restrict__ w,
                                           float* __restrict__ h, int n_nodes) {
    int gid = blockIdx.x * 256 + threadIdx.x;
    int n = gid >> 8;       // 256 float4 per row
    int c4 = gid & 255;
    if (n >= n_nodes) return;
    float x0 = x[n * 4 + 0], x1 = x[n * 4 + 1], x2 = x[n * 4 + 2], x3 = x[n * 4 + 3];
    const float4* w4 = (const float4*)w;
    float4 w0 = w4[0 * 256 + c4], w1 = w4[1 * 256 + c4],
           w2 = w4[2 * 256 + c4], w3 = w4[3 * 256 + c4];
    float4 r;
    r.x = x0 * w0.x + x1 * w1.x + x2 * w2.x + x3 * w3.x;
    r.y = x0 * w0.y + x1 * w1.y + x2 * w2.y + x3 * w3.y;
    r.z = x0 * w0.z + x1 * w1.z + x2 * w2.z + x3 * w3.z;
    r.w = x0 * w0.w + x1 * w1.w + x2 * w2.w + x3 * w3.w;
    ((float4*)h)[n * 256 + c4] = r;
}

// ---------------- a_s[n,h] = <h[n,h,:], att_src[h,:]>, same for a_d ----------------
__global__ void __launch_bounds__(256) k_scores(const float* __restrict__ h,
                                                const float* __restrict__ att_src,
                                                const float* __restrict__ att_dst,
                                                float* __restrict__ a_s,
                                                float* __restrict__ a_d, int n_nodes) {
    int lane = threadIdx.x & 63;
    int wave = threadIdx.x >> 6;
    int p = blockIdx.x * 4 + wave;           // p = n*8 + head
    if (p >= n_nodes * HEADS) return;
    int n = p >> 3, hh = p & 7;
    const float2* hv  = (const float2*)(h + (size_t)n * CMODEL + hh * DHEAD);
    const float2* sv  = (const float2*)(att_src + hh * DHEAD);
    const float2* dv  = (const float2*)(att_dst + hh * DHEAD);
    float2 hx = hv[lane], sa = sv[lane], da = dv[lane];
    float ps = hx.x * sa.x + hx.y * sa.y;
    float pd = hx.x * da.x + hx.y * da.y;
    for (int off = 32; off > 0; off >>= 1) {
        ps += __shfl_down(ps, off);
        pd += __shfl_down(pd, off);
    }
    if (lane == 0) { a_s[p] = ps; a_d[p] = pd; }
}

// ---------------- degree count over dst (incl. self loops) ----------------
__global__ void __launch_bounds__(256) k_count(const int* __restrict__ ei,
                                               int* __restrict__ deg,
                                               int n_nodes, int n_edges) {
    int e = blockIdx.x * 256 + threadIdx.x;
    int etot = n_edges + n_nodes;
    if (e >= etot) return;
    int dst = (e < n_edges) ? ei[n_edges + e] : (e - n_edges);
    atomicAdd(&deg[dst], 1);
}

// ---------------- exclusive scan -> rowptr (single block) ----------------
__global__ void __launch_bounds__(1024) k_scan(const int* __restrict__ deg,
                                               int* __restrict__ rowptr, int n) {
    __shared__ int temp[1024];
    __shared__ int carry_s;
    int tid = threadIdx.x;
    if (tid == 0) { carry_s = 0; rowptr[0] = 0; }
    __syncthreads();
    for (int base = 0; base < n; base += 1024) {
        int i = base + tid;
        int v = (i < n) ? deg[i] : 0;
        temp[tid] = v;
        __syncthreads();
        for (int off = 1; off < 1024; off <<= 1) {
            int add = (tid >= off) ? temp[tid - off] : 0;
            __syncthreads();
            temp[tid] += add;
            __syncthreads();
        }
        int incl = temp[tid] + carry_s;
        if (i < n) rowptr[i + 1] = incl;
        __syncthreads();                 // everyone has read carry_s
        if (tid == 1023) carry_s = incl;
        __syncthreads();
    }
}

// ---------------- scatter edges into CSR (by dst) ----------------
__global__ void __launch_bounds__(256) k_scatter(const int* __restrict__ ei,
                                                 const int* __restrict__ rowptr,
                                                 int* __restrict__ cursor,
                                                 int* __restrict__ csr_src,
                                                 int n_nodes, int n_edges) {
    int e = blockIdx.x * 256 + threadIdx.x;
    int etot = n_edges + n_nodes;
    if (e >= etot) return;
    int s, d;
    if (e < n_edges) { s = ei[e]; d = ei[n_edges + e]; }
    else             { s = d = e - n_edges; }
    int pos = atomicAdd(&cursor[d], 1);
    csr_src[rowptr[d] + pos] = s;
}

// ---------------- dinv = 1/sqrt(deg) ----------------
__global__ void __launch_bounds__(256) k_dinv(const int* __restrict__ deg,
                                              float* __restrict__ dinv, int n) {
    int i = blockIdx.x * 256 + threadIdx.x;
    if (i >= n) return;
    int dg = deg[i];
    dinv[i] = (dg > 0) ? (1.0f / sqrtf((float)dg)) : 0.0f;
}

// ---------------- segmented softmax per (dst node, head) ----------------
__global__ void __launch_bounds__(256) k_softmax(const float* __restrict__ a_s,
                                                 const float* __restrict__ a_d,
                                                 const int* __restrict__ rowptr,
                                                 const int* __restrict__ csr_src,
                                                 float* __restrict__ alpha, int n_nodes) {
    int p = blockIdx.x * 256 + threadIdx.x;   // p = n*8 + head
    if (p >= n_nodes * HEADS) return;
    int n = p >> 3, hh = p & 7;
    int r0 = rowptr[n], r1 = rowptr[n + 1];
    float ad = a_d[n * 8 + hh];
    float m = -1e30f;
    for (int r = r0; r < r1; r++) {
        int s = csr_src[r];
        float e = a_s[s * 8 + hh] + ad;
        e = (e > 0.0f) ? e : 0.2f * e;       // leaky relu
        alpha[r * 8 + hh] = e;
        m = fmaxf(m, e);
    }
    float sum = 0.0f;
    for (int r = r0; r < r1; r++) {
        float ex = expf(alpha[r * 8 + hh] - m);
        alpha[r * 8 + hh] = ex;
        sum += ex;
    }
    float inv = 1.0f / sum;
    for (int r = r0; r < r1; r++) alpha[r * 8 + hh] *= inv;
}

// ---------------- GAT aggregate + bias + gelu: one wave per node ----------------
__global__ void __launch_bounds__(256) k_gat_agg(const float* __restrict__ h,
                                                 const float* __restrict__ alpha,
                                                 const int* __restrict__ rowptr,
                                                 const int* __restrict__ csr_src,
                                                 const float* __restrict__ bias,
                                                 float* __restrict__ out, int n_nodes) {
    int lane = threadIdx.x & 63;
    int wave = threadIdx.x >> 6;
    int n = blockIdx.x * 4 + wave;
    if (n >= n_nodes) return;
    float4 acc0 = {0, 0, 0, 0}, acc1 = {0, 0, 0, 0}, acc2 = {0, 0, 0, 0}, acc3 = {0, 0, 0, 0};
    int r0 = rowptr[n], r1 = rowptr[n + 1];
    int hbase = lane >> 5;   // head low bit: lanes 0-31 -> even heads, 32-63 -> odd
    for (int r = r0; r < r1; r++) {
        int s = csr_src[r];
        const float4* hp = (const float4*)(h + (size_t)s * CMODEL);
        float a0 = alpha[r * 8 + 0 + hbase];
        float a1 = alpha[r * 8 + 2 + hbase];
        float a2 = alpha[r * 8 + 4 + hbase];
        float a3 = alpha[r * 8 + 6 + hbase];
        float4 v0 = hp[0 * 64 + lane];
        float4 v1 = hp[1 * 64 + lane];
        float4 v2 = hp[2 * 64 + lane];
        float4 v3 = hp[3 * 64 + lane];
        acc0.x += a0 * v0.x; acc0.y += a0 * v0.y; acc0.z += a0 * v0.z; acc0.w += a0 * v0.w;
        acc1.x += a1 * v1.x; acc1.y += a1 * v1.y; acc1.z += a1 * v1.z; acc1.w += a1 * v1.w;
        acc2.x += a2 * v2.x; acc2.y += a2 * v2.y; acc2.z += a2 * v2.z; acc2.w += a2 * v2.w;
        acc3.x += a3 * v3.x; acc3.y += a3 * v3.y; acc3.z += a3 * v3.z; acc3.w += a3 * v3.w;
    }
    const float4* b4 = (const float4*)bias;
    float4* o4 = (float4*)(out + (size_t)n * CMODEL);
    float4 bb, rr;
    bb = b4[0 * 64 + lane];
    rr.x = gelu_exact(acc0.x + bb.x); rr.y = gelu_exact(acc0.y + bb.y);
    rr.z = gelu_exact(acc0.z + bb.z); rr.w = gelu_exact(acc0.w + bb.w);
    o4[0 * 64 + lane] = rr;
    bb = b4[1 * 64 + lane];
    rr.x = gelu_exact(acc1.x + bb.x); rr.y = gelu_exact(acc1.y + bb.y);
    rr.z = gelu_exact(acc1.z + bb.z); rr.w = gelu_exact(acc1.w + bb.w);
    o4[1 * 64 + lane] = rr;
    bb = b4[2 * 64 + lane];
    rr.x = gelu_exact(acc2.x + bb.x); rr.y = gelu_exact(acc2.y + bb.y);
    rr.z = gelu_exact(acc2.z + bb.z); rr.w = gelu_exact(acc2.w + bb.w);
    o4[2 * 64 + lane] = rr;
    bb = b4[3 * 64 + lane];
    rr.x = gelu_exact(acc3.x + bb.x); rr.y = gelu_exact(acc3.y + bb.y);
    rr.z = gelu_exact(acc3.z + bb.z); rr.w = gelu_exact(acc3.w + bb.w);
    o4[3 * 64 + lane] = rr;
}

// ---------------- generic mm: out[N,128] = A[N,K] @ W[K,128], 16 rows/block ----------------
__global__ void __launch_bounds__(256) k_mm(const float* __restrict__ A,
                                            const float* __restrict__ W,
                                            float* __restrict__ out,
                                            int n_nodes, int K) {
    int c = threadIdx.x & 127;
    int rs = threadIdx.x >> 7;            // 0 or 1
    int row0 = blockIdx.x * 16 + rs * 8;
    if (row0 >= n_nodes) return;
    float acc[8] = {0, 0, 0, 0, 0, 0, 0, 0};
    const float4* Ap = (const float4*)(A + (size_t)row0 * K);
    int K4 = K >> 2;
    for (int k4 = 0; k4 < K4; k4++) {
        int k = k4 * 4;
        float w0 = W[(k + 0) * 128 + c];
        float w1 = W[(k + 1) * 128 + c];
        float w2 = W[(k + 2) * 128 + c];
        float w3 = W[(k + 3) * 128 + c];
#pragma unroll
        for (int i = 0; i < 8; i++) {
            float4 av = Ap[(size_t)i * K4 + k4];
            acc[i] += av.x * w0 + av.y * w1 + av.z * w2 + av.w * w3;
        }
    }
#pragma unroll
    for (int i = 0; i < 8; i++) {
        int row = row0 + i;
        if (row < n_nodes) out[(size_t)row * 128 + c] = acc[i];
    }
}

// ---------------- GCN aggregate: out[n,c] = dinv[n]*sum dinv[s]*t[s,c] + b, opt gelu ----------------
__global__ void __launch_bounds__(256) k_gcn_agg(const float* __restrict__ t,
                                                 const float* __restrict__ dinv,
                                                 const int* __restrict__ rowptr,
                                                 const int* __restrict__ csr_src,
                                                 const float* __restrict__ bias,
                                                 float* __restrict__ out,
                                                 int n_nodes, int apply_gelu) {
    int c = threadIdx.x & 127;
    int half = threadIdx.x >> 7;
    int n = blockIdx.x * 2 + half;
    if (n >= n_nodes) return;
    float acc = 0.0f;
    int r0 = rowptr[n], r1 = rowptr[n + 1];
    for (int r = r0; r < r1; r++) {
        int s = csr_src[r];
        acc += dinv[s] * t[(size_t)s * 128 + c];
    }
    float v = acc * dinv[n] + bias[c];
    if (apply_gelu) v = gelu_exact(v);
    out[(size_t)n * 128 + c] = v;
}

extern "C" void kernel_launch(void* const* d_in, const int* in_sizes, int n_in,
                              void* d_out, int out_size, void* d_ws, size_t ws_size,
                              hipStream_t stream) {
    const float* x        = (const float*)d_in[0];
    const int*   ei       = (const int*)d_in[1];
    const float* gat_w    = (const float*)d_in[2];
    const float* att_src  = (const float*)d_in[3];
    const float* att_dst  = (const float*)d_in[4];
    const float* gat_b    = (const float*)d_in[5];
    const float* gcn1_w   = (const float*)d_in[6];
    const float* gcn1_b   = (const float*)d_in[7];
    const float* gcn2_w   = (const float*)d_in[8];
    const float* gcn2_b   = (const float*)d_in[9];
    float* out = (float*)d_out;

    int N = in_sizes[0] / 4;        // 10000
    int E = in_sizes[1] / 2;        // 160000
    int Etot = E + N;               // 170000

    char* base = (char*)d_ws;
    // region A: h lives until GAT agg; reused for t/out2/t2 afterwards
    float* h      = (float*)(base);                              // N*1024 f32 = 40.96 MB
    float* out1   = (float*)(base + 40960000);                   // N*1024 f32 = 40.96 MB
    size_t off = 81920000;
    float* a_s    = (float*)(base + off); off += (size_t)N * 8 * 4;
    float* a_d    = (float*)(base + off); off += (size_t)N * 8 * 4;
    float* alpha  = (float*)(base + off); off += (size_t)Etot * 8 * 4;
    int*   deg    = (int*)(base + off);   off += (size_t)N * 4;
    float* dinv   = (float*)(base + off); off += (size_t)N * 4;
    int*   rowptr = (int*)(base + off);   off += ((size_t)N + 1) * 4 + 60; off &= ~(size_t)63;
    int*   cursor = (int*)(base + off);   off += (size_t)N * 4;
    int*   csrsrc = (int*)(base + off);   off += (size_t)Etot * 4;
    // reuse h region (dead after k_gat_agg) for GCN intermediates
    float* t      = (float*)(base);                              // N*128 f32 = 5.12 MB
    float* out2   = (float*)(base + 5120000);
    float* t2     = (float*)(base + 10240000);

    hipMemsetAsync(deg, 0, (size_t)N * 4, stream);
    hipMemsetAsync(cursor, 0, (size_t)N * 4, stream);

    // GAT linear + scores
    k_h<<<N, 256, 0, stream>>>(x, gat_w, h, N);
    k_scores<<<(N * HEADS + 3) / 4, 256, 0, stream>>>(h, att_src, att_dst, a_s, a_d, N);

    // CSR build
    k_count<<<(Etot + 255) / 256, 256, 0, stream>>>(ei, deg, N, E);
    k_scan<<<1, 1024, 0, stream>>>(deg, rowptr, N);
    k_scatter<<<(Etot + 255) / 256, 256, 0, stream>>>(ei, rowptr, cursor, csrsrc, N, E);
    k_dinv<<<(N + 255) / 256, 256, 0, stream>>>(deg, dinv, N);

    // edge softmax
    k_softmax<<<(N * HEADS + 255) / 256, 256, 0, stream>>>(a_s, a_d, rowptr, csrsrc, alpha, N);

    // GAT aggregate + bias + gelu -> out1 [N,1024]
    k_gat_agg<<<(N + 3) / 4, 256, 0, stream>>>(h, alpha, rowptr, csrsrc, gat_b, out1, N);

    // GCN1: t = out1 @ gcn1_w ; out2 = gelu(D^-1/2 A D^-1/2 t + b)
    k_mm<<<(N + 15) / 16, 256, 0, stream>>>(out1, gcn1_w, t, N, 1024);
    k_gcn_agg<<<(N + 1) / 2, 256, 0, stream>>>(t, dinv, rowptr, csrsrc, gcn1_b, out2, N, 1);

    // GCN2: t2 = out2 @ gcn2_w ; out = D^-1/2 A D^-1/2 t2 + b
    k_mm<<<(N + 15) / 16, 256, 0, stream>>>(out2, gcn2_w, t2, N, 128);
    k_gcn_agg<<<(N + 1) / 2, 256, 0, stream>>>(t2, dinv, rowptr, csrsrc, gcn2_b, out, N, 0);
}

// Round 2
// 441.956 us; speedup vs baseline: 1.2682x; 1.2682x over previous
//
#include <hip/hip_runtime.h>
#include <math.h>

#define HEADS 8
#define DHEAD 128
#define CMODEL 1024   // HEADS*DHEAD

__device__ __forceinline__ float gelu_exact(float x) {
    return 0.5f * x * (1.0f + erff(x * 0.70710678118654752440f));
}

// ---------------- h = x @ gat_w  (x: [N,4], w: [4,1024]) ----------------
__global__ void __launch_bounds__(256) k_h(const float* __restrict__ x,
                                           const float* __restrict__ w,
                                           float* __restrict__ h, int n_nodes) {
    int gid = blockIdx.x * 256 + threadIdx.x;
    int n = gid >> 8;       // 256 float4 per row
    int c4 = gid & 255;
    if (n >= n_nodes) return;
    float x0 = x[n * 4 + 0], x1 = x[n * 4 + 1], x2 = x[n * 4 + 2], x3 = x[n * 4 + 3];
    const float4* w4 = (const float4*)w;
    float4 w0 = w4[0 * 256 + c4], w1 = w4[1 * 256 + c4],
           w2 = w4[2 * 256 + c4], w3 = w4[3 * 256 + c4];
    float4 r;
    r.x = x0 * w0.x + x1 * w1.x + x2 * w2.x + x3 * w3.x;
    r.y = x0 * w0.y + x1 * w1.y + x2 * w2.y + x3 * w3.y;
    r.z = x0 * w0.z + x1 * w1.z + x2 * w2.z + x3 * w3.z;
    r.w = x0 * w0.w + x1 * w1.w + x2 * w2.w + x3 * w3.w;
    ((float4*)h)[n * 256 + c4] = r;
}

// ---------------- a_s[n,h] = <h[n,h,:], att_src[h,:]>, same for a_d ----------------
__global__ void __launch_bounds__(256) k_scores(const float* __restrict__ h,
                                                const float* __restrict__ att_src,
                                                const float* __restrict__ att_dst,
                                                float* __restrict__ a_s,
                                                float* __restrict__ a_d, int n_nodes) {
    int lane = threadIdx.x & 63;
    int wave = threadIdx.x >> 6;
    int p = blockIdx.x * 4 + wave;           // p = n*8 + head
    if (p >= n_nodes * HEADS) return;
    int n = p >> 3, hh = p & 7;
    const float2* hv  = (const float2*)(h + (size_t)n * CMODEL + hh * DHEAD);
    const float2* sv  = (const float2*)(att_src + hh * DHEAD);
    const float2* dv  = (const float2*)(att_dst + hh * DHEAD);
    float2 hx = hv[lane], sa = sv[lane], da = dv[lane];
    float ps = hx.x * sa.x + hx.y * sa.y;
    float pd = hx.x * da.x + hx.y * da.y;
    for (int off = 32; off > 0; off >>= 1) {
        ps += __shfl_down(ps, off);
        pd += __shfl_down(pd, off);
    }
    if (lane == 0) { a_s[p] = ps; a_d[p] = pd; }
}

// ---------------- degree count over dst (incl. self loops) ----------------
__global__ void __launch_bounds__(256) k_count(const int* __restrict__ ei,
                                               int* __restrict__ deg,
                                               int n_nodes, int n_edges) {
    int e = blockIdx.x * 256 + threadIdx.x;
    int etot = n_edges + n_nodes;
    if (e >= etot) return;
    int dst = (e < n_edges) ? ei[n_edges + e] : (e - n_edges);
    atomicAdd(&deg[dst], 1);
}

// ---------------- exclusive scan -> rowptr (single block, shfl-based) ----------------
__global__ void __launch_bounds__(1024) k_scan(const int* __restrict__ deg,
                                               int* __restrict__ rowptr, int n) {
    __shared__ int wsum[16];
    __shared__ int carry_s;
    int tid = threadIdx.x;
    int lane = tid & 63, w = tid >> 6;
    if (tid == 0) { carry_s = 0; rowptr[0] = 0; }
    __syncthreads();
    for (int base = 0; base < n; base += 1024) {
        int i = base + tid;
        int v = (i < n) ? deg[i] : 0;
        // inclusive scan within wave
        int s = v;
        #pragma unroll
        for (int off = 1; off < 64; off <<= 1) {
            int t = __shfl_up(s, off);
            if (lane >= off) s += t;
        }
        if (lane == 63) wsum[w] = s;
        __syncthreads();
        int woff = 0;
        #pragma unroll
        for (int j = 0; j < 16; j++) woff += (j < w) ? wsum[j] : 0;
        int incl = s + woff + carry_s;
        if (i < n) rowptr[i + 1] = incl;
        __syncthreads();                 // everyone done reading carry_s / wsum
        if (tid == 1023) carry_s = incl;
        __syncthreads();
    }
}

// ---------------- scatter edges into CSR (by dst) ----------------
__global__ void __launch_bounds__(256) k_scatter(const int* __restrict__ ei,
                                                 const int* __restrict__ rowptr,
                                                 int* __restrict__ cursor,
                                                 int* __restrict__ csr_src,
                                                 int n_nodes, int n_edges) {
    int e = blockIdx.x * 256 + threadIdx.x;
    int etot = n_edges + n_nodes;
    if (e >= etot) return;
    int s, d;
    if (e < n_edges) { s = ei[e]; d = ei[n_edges + e]; }
    else             { s = d = e - n_edges; }
    int pos = atomicAdd(&cursor[d], 1);
    csr_src[rowptr[d] + pos] = s;
}

// ---------------- dinv = 1/sqrt(deg) ----------------
__global__ void __launch_bounds__(256) k_dinv(const int* __restrict__ deg,
                                              float* __restrict__ dinv, int n) {
    int i = blockIdx.x * 256 + threadIdx.x;
    if (i >= n) return;
    int dg = deg[i];
    dinv[i] = (dg > 0) ? (1.0f / sqrtf((float)dg)) : 0.0f;
}

// ---------------- segmented softmax per (dst node, head) ----------------
__global__ void __launch_bounds__(256) k_softmax(const float* __restrict__ a_s,
                                                 const float* __restrict__ a_d,
                                                 const int* __restrict__ rowptr,
                                                 const int* __restrict__ csr_src,
                                                 float* __restrict__ alpha, int n_nodes) {
    int p = blockIdx.x * 256 + threadIdx.x;   // p = n*8 + head
    if (p >= n_nodes * HEADS) return;
    int n = p >> 3, hh = p & 7;
    int r0 = rowptr[n], r1 = rowptr[n + 1];
    float ad = a_d[n * 8 + hh];
    float m = -1e30f;
    for (int r = r0; r < r1; r++) {
        int s = csr_src[r];
        float e = a_s[s * 8 + hh] + ad;
        e = (e > 0.0f) ? e : 0.2f * e;       // leaky relu
        alpha[r * 8 + hh] = e;
        m = fmaxf(m, e);
    }
    float sum = 0.0f;
    for (int r = r0; r < r1; r++) {
        float ex = expf(alpha[r * 8 + hh] - m);
        alpha[r * 8 + hh] = ex;
        sum += ex;
    }
    float inv = 1.0f / sum;
    for (int r = r0; r < r1; r++) alpha[r * 8 + hh] *= inv;
}

// ---------------- GAT aggregate + bias + gelu: one wave per node ----------------
__global__ void __launch_bounds__(256) k_gat_agg(const float* __restrict__ h,
                                                 const float* __restrict__ alpha,
                                                 const int* __restrict__ rowptr,
                                                 const int* __restrict__ csr_src,
                                                 const float* __restrict__ bias,
                                                 float* __restrict__ out, int n_nodes) {
    int lane = threadIdx.x & 63;
    int wave = threadIdx.x >> 6;
    int n = blockIdx.x * 4 + wave;
    if (n >= n_nodes) return;
    float4 acc0 = {0, 0, 0, 0}, acc1 = {0, 0, 0, 0}, acc2 = {0, 0, 0, 0}, acc3 = {0, 0, 0, 0};
    int r0 = rowptr[n], r1 = rowptr[n + 1];
    int hbase = lane >> 5;   // head low bit: lanes 0-31 -> even heads, 32-63 -> odd
    for (int r = r0; r < r1; r++) {
        int s = csr_src[r];
        const float4* hp = (const float4*)(h + (size_t)s * CMODEL);
        float a0 = alpha[r * 8 + 0 + hbase];
        float a1 = alpha[r * 8 + 2 + hbase];
        float a2 = alpha[r * 8 + 4 + hbase];
        float a3 = alpha[r * 8 + 6 + hbase];
        float4 v0 = hp[0 * 64 + lane];
        float4 v1 = hp[1 * 64 + lane];
        float4 v2 = hp[2 * 64 + lane];
        float4 v3 = hp[3 * 64 + lane];
        acc0.x += a0 * v0.x; acc0.y += a0 * v0.y; acc0.z += a0 * v0.z; acc0.w += a0 * v0.w;
        acc1.x += a1 * v1.x; acc1.y += a1 * v1.y; acc1.z += a1 * v1.z; acc1.w += a1 * v1.w;
        acc2.x += a2 * v2.x; acc2.y += a2 * v2.y; acc2.z += a2 * v2.z; acc2.w += a2 * v2.w;
        acc3.x += a3 * v3.x; acc3.y += a3 * v3.y; acc3.z += a3 * v3.z; acc3.w += a3 * v3.w;
    }
    const float4* b4 = (const float4*)bias;
    float4* o4 = (float4*)(out + (size_t)n * CMODEL);
    float4 bb, rr;
    bb = b4[0 * 64 + lane];
    rr.x = gelu_exact(acc0.x + bb.x); rr.y = gelu_exact(acc0.y + bb.y);
    rr.z = gelu_exact(acc0.z + bb.z); rr.w = gelu_exact(acc0.w + bb.w);
    o4[0 * 64 + lane] = rr;
    bb = b4[1 * 64 + lane];
    rr.x = gelu_exact(acc1.x + bb.x); rr.y = gelu_exact(acc1.y + bb.y);
    rr.z = gelu_exact(acc1.z + bb.z); rr.w = gelu_exact(acc1.w + bb.w);
    o4[1 * 64 + lane] = rr;
    bb = b4[2 * 64 + lane];
    rr.x = gelu_exact(acc2.x + bb.x); rr.y = gelu_exact(acc2.y + bb.y);
    rr.z = gelu_exact(acc2.z + bb.z); rr.w = gelu_exact(acc2.w + bb.w);
    o4[2 * 64 + lane] = rr;
    bb = b4[3 * 64 + lane];
    rr.x = gelu_exact(acc3.x + bb.x); rr.y = gelu_exact(acc3.y + bb.y);
    rr.z = gelu_exact(acc3.z + bb.z); rr.w = gelu_exact(acc3.w + bb.w);
    o4[3 * 64 + lane] = rr;
}

// ---------------- tiled mm: out[N,128] = A[N,K] @ W[K,128] ----------------
// Block: 32 rows x 128 cols. Thread: 4 rows x 4 cols (16 accs).
// A staged in LDS (coalesced global load, broadcast b128 reads).
// W streamed from global (hot in L2: 512 KB).
#define MM_BK 16
#define MM_LDA 20   // 16 + 4 pad; row stride 80 B keeps 16 B alignment
__global__ void __launch_bounds__(256) k_mm(const float* __restrict__ A,
                                            const float* __restrict__ W,
                                            float* __restrict__ out,
                                            int n_nodes, int K) {
    __shared__ float As[32 * MM_LDA];
    int c0 = (threadIdx.x & 31) * 4;        // column base 0..124
    int rg = threadIdx.x >> 5;              // 0..7
    int r0 = rg * 4;                        // thread rows r0..r0+3 in tile
    int row_blk = blockIdx.x * 32;
    // staging assignment: each thread loads one float2
    int st_r = threadIdx.x >> 3;            // 0..31
    int st_g = threadIdx.x & 7;             // 0..7 (k offset st_g*2)
    int st_row = row_blk + st_r;
    float4 acc[4];
    acc[0] = make_float4(0, 0, 0, 0); acc[1] = make_float4(0, 0, 0, 0);
    acc[2] = make_float4(0, 0, 0, 0); acc[3] = make_float4(0, 0, 0, 0);

    for (int kk = 0; kk < K; kk += MM_BK) {
        __syncthreads();   // previous tile reads done
        float2 av = make_float2(0.0f, 0.0f);
        if (st_row < n_nodes)
            av = *(const float2*)(A + (size_t)st_row * K + kk + st_g * 2);
        *(float2*)&As[st_r * MM_LDA + st_g * 2] = av;
        __syncthreads();
        #pragma unroll
        for (int g = 0; g < 4; g++) {
            float4 a0 = *(const float4*)&As[(r0 + 0) * MM_LDA + g * 4];
            float4 a1 = *(const float4*)&As[(r0 + 1) * MM_LDA + g * 4];
            float4 a2 = *(const float4*)&As[(r0 + 2) * MM_LDA + g * 4];
            float4 a3 = *(const float4*)&As[(r0 + 3) * MM_LDA + g * 4];
            const float* wp = W + (size_t)(kk + g * 4) * 128 + c0;
            float4 w0 = *(const float4*)(wp + 0 * 128);
            float4 w1 = *(const float4*)(wp + 1 * 128);
            float4 w2 = *(const float4*)(wp + 2 * 128);
            float4 w3 = *(const float4*)(wp + 3 * 128);
            acc[0].x += a0.x * w0.x + a0.y * w1.x + a0.z * w2.x + a0.w * w3.x;
            acc[0].y += a0.x * w0.y + a0.y * w1.y + a0.z * w2.y + a0.w * w3.y;
            acc[0].z += a0.x * w0.z + a0.y * w1.z + a0.z * w2.z + a0.w * w3.z;
            acc[0].w += a0.x * w0.w + a0.y * w1.w + a0.z * w2.w + a0.w * w3.w;
            acc[1].x += a1.x * w0.x + a1.y * w1.x + a1.z * w2.x + a1.w * w3.x;
            acc[1].y += a1.x * w0.y + a1.y * w1.y + a1.z * w2.y + a1.w * w3.y;
            acc[1].z += a1.x * w0.z + a1.y * w1.z + a1.z * w2.z + a1.w * w3.z;
            acc[1].w += a1.x * w0.w + a1.y * w1.w + a1.z * w2.w + a1.w * w3.w;
            acc[2].x += a2.x * w0.x + a2.y * w1.x + a2.z * w2.x + a2.w * w3.x;
            acc[2].y += a2.x * w0.y + a2.y * w1.y + a2.z * w2.y + a2.w * w3.y;
            acc[2].z += a2.x * w0.z + a2.y * w1.z + a2.z * w2.z + a2.w * w3.z;
            acc[2].w += a2.x * w0.w + a2.y * w1.w + a2.z * w2.w + a2.w * w3.w;
            acc[3].x += a3.x * w0.x + a3.y * w1.x + a3.z * w2.x + a3.w * w3.x;
            acc[3].y += a3.x * w0.y + a3.y * w1.y + a3.z * w2.y + a3.w * w3.y;
            acc[3].z += a3.x * w0.z + a3.y * w1.z + a3.z * w2.z + a3.w * w3.z;
            acc[3].w += a3.x * w0.w + a3.y * w1.w + a3.z * w2.w + a3.w * w3.w;
        }
    }
    #pragma unroll
    for (int i = 0; i < 4; i++) {
        int row = row_blk + r0 + i;
        if (row < n_nodes)
            *(float4*)(out + (size_t)row * 128 + c0) = acc[i];
    }
}

// ---------------- GCN aggregate: out[n,c] = dinv[n]*sum dinv[s]*t[s,c] + b, opt gelu ----------------
__global__ void __launch_bounds__(256) k_gcn_agg(const float* __restrict__ t,
                                                 const float* __restrict__ dinv,
                                                 const int* __restrict__ rowptr,
                                                 const int* __restrict__ csr_src,
                                                 const float* __restrict__ bias,
                                                 float* __restrict__ out,
                                                 int n_nodes, int apply_gelu) {
    int c = threadIdx.x & 127;
    int half = threadIdx.x >> 7;
    int n = blockIdx.x * 2 + half;
    if (n >= n_nodes) return;
    float acc = 0.0f;
    int r0 = rowptr[n], r1 = rowptr[n + 1];
    for (int r = r0; r < r1; r++) {
        int s = csr_src[r];
        acc += dinv[s] * t[(size_t)s * 128 + c];
    }
    float v = acc * dinv[n] + bias[c];
    if (apply_gelu) v = gelu_exact(v);
    out[(size_t)n * 128 + c] = v;
}

extern "C" void kernel_launch(void* const* d_in, const int* in_sizes, int n_in,
                              void* d_out, int out_size, void* d_ws, size_t ws_size,
                              hipStream_t stream) {
    const float* x        = (const float*)d_in[0];
    const int*   ei       = (const int*)d_in[1];
    const float* gat_w    = (const float*)d_in[2];
    const float* att_src  = (const float*)d_in[3];
    const float* att_dst  = (const float*)d_in[4];
    const float* gat_b    = (const float*)d_in[5];
    const float* gcn1_w   = (const float*)d_in[6];
    const float* gcn1_b   = (const float*)d_in[7];
    const float* gcn2_w   = (const float*)d_in[8];
    const float* gcn2_b   = (const float*)d_in[9];
    float* out = (float*)d_out;

    int N = in_sizes[0] / 4;        // 10000
    int E = in_sizes[1] / 2;        // 160000
    int Etot = E + N;               // 170000

    char* base = (char*)d_ws;
    float* h      = (float*)(base);                              // N*1024 f32 = 40.96 MB
    float* out1   = (float*)(base + 40960000);                   // N*1024 f32 = 40.96 MB
    size_t off = 81920000;
    float* a_s    = (float*)(base + off); off += (size_t)N * 8 * 4;
    float* a_d    = (float*)(base + off); off += (size_t)N * 8 * 4;
    float* alpha  = (float*)(base + off); off += (size_t)Etot * 8 * 4;
    int*   deg    = (int*)(base + off);   off += (size_t)N * 4;
    float* dinv   = (float*)(base + off); off += (size_t)N * 4;
    int*   rowptr = (int*)(base + off);   off += ((size_t)N + 1) * 4 + 60; off &= ~(size_t)63;
    int*   cursor = (int*)(base + off);   off += (size_t)N * 4;
    int*   csrsrc = (int*)(base + off);   off += (size_t)Etot * 4;
    // reuse h region (dead after k_gat_agg) for GCN intermediates
    float* t      = (float*)(base);                              // N*128 f32 = 5.12 MB
    float* out2   = (float*)(base + 5120000);
    float* t2     = (float*)(base + 10240000);

    hipMemsetAsync(deg, 0, (size_t)N * 4, stream);
    hipMemsetAsync(cursor, 0, (size_t)N * 4, stream);

    // GAT linear + scores
    k_h<<<N, 256, 0, stream>>>(x, gat_w, h, N);
    k_scores<<<(N * HEADS + 3) / 4, 256, 0, stream>>>(h, att_src, att_dst, a_s, a_d, N);

    // CSR build
    k_count<<<(Etot + 255) / 256, 256, 0, stream>>>(ei, deg, N, E);
    k_scan<<<1, 1024, 0, stream>>>(deg, rowptr, N);
    k_scatter<<<(Etot + 255) / 256, 256, 0, stream>>>(ei, rowptr, cursor, csrsrc, N, E);
    k_dinv<<<(N + 255) / 256, 256, 0, stream>>>(deg, dinv, N);

    // edge softmax
    k_softmax<<<(N * HEADS + 255) / 256, 256, 0, stream>>>(a_s, a_d, rowptr, csrsrc, alpha, N);

    // GAT aggregate + bias + gelu -> out1 [N,1024]
    k_gat_agg<<<(N + 3) / 4, 256, 0, stream>>>(h, alpha, rowptr, csrsrc, gat_b, out1, N);

    // GCN1: t = out1 @ gcn1_w ; out2 = gelu(D^-1/2 A D^-1/2 t + b)
    k_mm<<<(N + 31) / 32, 256, 0, stream>>>(out1, gcn1_w, t, N, 1024);
    k_gcn_agg<<<(N + 1) / 2, 256, 0, stream>>>(t, dinv, rowptr, csrsrc, gcn1_b, out2, N, 1);

    // GCN2: t2 = out2 @ gcn2_w ; out = D^-1/2 A D^-1/2 t2 + b
    k_mm<<<(N + 31) / 32, 256, 0, stream>>>(out2, gcn2_w, t2, N, 128);
    k_gcn_agg<<<(N + 1) / 2, 256, 0, stream>>>(t2, dinv, rowptr, csrsrc, gcn2_b, out, N, 0);
}